// Round 14
// baseline (75.491 us; speedup 1.0000x reference)
//
#include <hip/hip_runtime.h>
#include <hip/hip_bf16.h>
#include <stdint.h>

// out[n, m=c*64+i, r] = sum_j (S*W[c,r,i,j]) * X[n,r,j],  S = DELTA_G*DELTA_V
// N=4096, M=1024 (c=16 x i=64), R=16, K=64.  GMIN terms cancel exactly.
//
// Round-14: two-kernel plan.
//  pre:  X fp32 -> Xt bf16 in d_ws, laid out in EXACT per-wave fragment order
//        (frag(tg,r,ks)[lane] contiguous 1KB) - coalesced reads, L2-merged writes.
//  main: no X staging at all. B-frag = one contiguous wave load from Xt (L2).
//        LDS = O-tile only (16 x 514dw = 32.9KB, round-13 conflict-free) ->
//        4 blocks/CU = 32 waves/CU. 2 light barriers/iter. nt stores drain
//        under next iter's loads+MFMAs. No cvt in loop, no xp regs.
//  Falls back to the proven round-13 kernel if ws_size < 8MB.

using bf16x8 = __attribute__((ext_vector_type(8))) short;
using f32x4  = __attribute__((ext_vector_type(4))) float;
using f32x2  = __attribute__((ext_vector_type(2))) float;

#define OPITCH_DW 514          // O: dwords per n-row (conflict-free ep1/ep2)
#define OLDS_BYTES (16 * OPITCH_DW * 4)   // 32896 -> 4 blocks/CU

// LDS-only barrier: order ds ops across waves without draining the VM queue.
#define BARRIER() asm volatile("s_waitcnt lgkmcnt(0)\n\ts_barrier" ::: "memory")

__device__ inline bf16x8 cvt8v(float4 a, float4 b) {
  union { bf16x8 v; __hip_bfloat162 h[4]; } r;
  r.h[0] = __float22bfloat162_rn(float2{a.x, a.y});
  r.h[1] = __float22bfloat162_rn(float2{a.z, a.w});
  r.h[2] = __float22bfloat162_rn(float2{b.x, b.y});
  r.h[3] = __float22bfloat162_rn(float2{b.z, b.w});
  return r.v;
}

// ---------------- pre-pass: X[n][r][j] fp32 -> Xt frags bf16 ----------------
// frag index fi = (((tg*16 + r)*2 + ks)*4 + lk)*16 + lr,  n = tg*16+lr,
// j = ks*32 + lk*8 + e.  Wave (tg,r,ks) then reads frags [base .. base+64).
__global__ __launch_bounds__(512, 8)
void crxb_pre(const float* __restrict__ X, ushort* __restrict__ Xt) {
  const int g  = blockIdx.x * 512 + threadIdx.x;   // 0..524287
  const int n  = g >> 7;
  const int r  = (g >> 3) & 15;
  const int j0 = g & 7;
  const float* gx = X + (((size_t)n * 16) + r) * 64 + j0 * 8;
  bf16x8 v = cvt8v(*(const float4*)gx, *(const float4*)(gx + 4));
  const int ks = j0 >> 2, lk = j0 & 3;
  const size_t fi = ((((size_t)(n >> 4) * 16 + r) * 2 + ks) * 4 + lk) * 16 + (n & 15);
  *(bf16x8*)(Xt + fi * 8) = v;   // normal store: L2 merges the 16B partials
}

// ---------------- main: MFMA from Xt-frags, O-transpose in LDS --------------
__global__ __launch_bounds__(512, 8)
void crxb_main(const ushort* __restrict__ Xt, const float* __restrict__ W,
               float* __restrict__ out) {
  __shared__ float O[16 * OPITCH_DW];

  const int t   = threadIdx.x;
  const int bid = blockIdx.x;
  // 1024 blocks = 32 m-tiles x 32 n-groups (128 n each); all 32 m-blocks of
  // one n-group land on one XCD (bid%8) -> its 256KB Xt slice is L2-resident.
  const int xcd = bid & 7;
  const int ng  = xcd * 4 + ((bid >> 3) & 3);   // 0..31
  const int mt  = bid >> 5;                     // 0..31
  const int c  = mt >> 1;
  const int i0 = (mt & 1) << 5;
  const int m0 = mt << 5;

  const int wid = t >> 6;
  const int l   = t & 63;
  const int lr  = l & 15;            // A row (m within 16) / B col (n)
  const int lk  = l >> 4;            // k-subgroup 0..3
  const int r0w = wid << 1;          // wave owns r0w, r0w+1

  const float S = (float)((0.000333 - 3.33e-07) * (3.3 / 255.0));

  // ---- hoist A fragments: (S*W) fp32 global -> bf16 regs (once per block) ----
  bf16x8 A[2][2][2];                 // [rr][ks][a]
  #pragma unroll
  for (int rr = 0; rr < 2; ++rr)
    #pragma unroll
    for (int ks = 0; ks < 2; ++ks)
      #pragma unroll
      for (int a = 0; a < 2; ++a) {
        const float* gw = W + (((size_t)(c * 16 + r0w + rr) * 64) + (i0 + a * 16 + lr)) * 64
                            + ks * 32 + lk * 8;
        float4 wa = *(const float4*)gw;
        float4 wb = *(const float4*)(gw + 4);
        wa.x *= S; wa.y *= S; wa.z *= S; wa.w *= S;
        wb.x *= S; wb.y *= S; wb.z *= S; wb.w *= S;
        A[rr][ks][a] = cvt8v(wa, wb);
      }

  for (int it = 0; it < 8; ++it) {
    const int tg = ng * 8 + it;      // global n-tile 0..255
    const int n0 = tg * 16;

    // ---- compute: B-frags straight from Xt (contiguous 1KB per wave-load) ----
    f32x4 acc[2][2];                 // [rr][a]
    #pragma unroll
    for (int rr = 0; rr < 2; ++rr)
      #pragma unroll
      for (int a = 0; a < 2; ++a) acc[rr][a] = (f32x4){0.f, 0.f, 0.f, 0.f};

    #pragma unroll
    for (int rr = 0; rr < 2; ++rr) {
      const int r = r0w + rr;
      #pragma unroll
      for (int ks = 0; ks < 2; ++ks) {
        bf16x8 Bf = *(const bf16x8*)(Xt + ((((size_t)tg * 16 + r) * 2 + ks) * 64 + l) * 8);
        acc[rr][0] = __builtin_amdgcn_mfma_f32_16x16x32_bf16(A[rr][ks][0], Bf, acc[rr][0], 0, 0, 0);
        acc[rr][1] = __builtin_amdgcn_mfma_f32_16x16x32_bf16(A[rr][ks][1], Bf, acc[rr][1], 0, 0, 0);
      }
    }
    BARRIER();                       // prev iter's ep2 reads of O are done

    // ---- ep1: acc -> O (pitch 514dw, conflict-free f32x2) ----
    #pragma unroll
    for (int a = 0; a < 2; ++a)
      #pragma unroll
      for (int reg = 0; reg < 4; ++reg) {
        f32x2 v = {acc[0][a][reg], acc[1][a][reg]};
        const int mm = a * 16 + lk * 4 + reg;   // m within 32
        *(f32x2*)(O + (size_t)lr * OPITCH_DW + mm * 16 + r0w) = v;
      }
    BARRIER();

    // ---- ep2: O -> global; two b64 LDS reads -> one f32x4 nt store ----
    {
      const int n  = t >> 5;         // 0..15
      const int j0 = t & 31;
      const float* Or = O + (size_t)n * OPITCH_DW;
      float* gout = out + ((size_t)(n0 + n)) * 16384 + (size_t)m0 * 16;
      #pragma unroll
      for (int q = 0; q < 4; ++q) {
        const int u = (q * 32 + j0) * 4;        // dword offset in row
        f32x2 lo = *(const f32x2*)(Or + u);
        f32x2 hi = *(const f32x2*)(Or + u + 2);
        f32x4 v = {lo[0], lo[1], hi[0], hi[1]};
        __builtin_nontemporal_store(v, (f32x4*)(gout + u));
      }
    }
  }
}

// ---------------- fallback: proven round-13 kernel (59.9us) -----------------
#define NPT 16
#define NIT 16
#define PITCH_B 2064
#define BUFB 33024
#define LDS_BYTES (2*BUFB)

__global__ __launch_bounds__(512, 4)
void crxb_kernel(const float* __restrict__ X, const float* __restrict__ W,
                 float* __restrict__ out) {
  extern __shared__ char smem[];
  const int t   = threadIdx.x;
  const int bid = blockIdx.x;
  const int ngrp = ((bid & 7) << 1) | ((bid >> 3) & 1);
  const int mt   = bid >> 4;
  const int c  = mt >> 1;
  const int i0 = (mt & 1) << 5;
  const int m0 = mt << 5;
  const int wid = t >> 6;
  const int l   = t & 63;
  const int lr  = l & 15;
  const int lk  = l >> 4;
  const int r0w = wid << 1;
  const float S = (float)((0.000333 - 3.33e-07) * (3.3 / 255.0));

  bf16x8 A[2][2][2];
  #pragma unroll
  for (int rr = 0; rr < 2; ++rr)
    #pragma unroll
    for (int ks = 0; ks < 2; ++ks)
      #pragma unroll
      for (int a = 0; a < 2; ++a) {
        const float* gw = W + (((size_t)(c * 16 + r0w + rr) * 64) + (i0 + a * 16 + lr)) * 64
                            + ks * 32 + lk * 8;
        float4 wa = *(const float4*)gw;
        float4 wb = *(const float4*)(gw + 4);
        wa.x *= S; wa.y *= S; wa.z *= S; wa.w *= S;
        wb.x *= S; wb.y *= S; wb.z *= S; wb.w *= S;
        A[rr][ks][a] = cvt8v(wa, wb);
      }

  {
    #pragma unroll
    for (int p = 0; p < 4; ++p) {
      int u = p * 512 + t;
      int n = u >> 7, r = (u >> 3) & 15, k8 = u & 7;
      const float* gx = X + (((size_t)(ngrp * 256 + n) * 16) + r) * 64 + k8 * 8;
      *(bf16x8*)(smem + (size_t)n * PITCH_B + r * 128 + k8 * 16) =
          cvt8v(*(const float4*)gx, *(const float4*)(gx + 4));
    }
  }
  BARRIER();

  int cur = 0;
  for (int it = 0; it < NIT; ++it) {
    char* bufc = smem + cur * BUFB;
    char* bufn = smem + (cur ^ 1) * BUFB;
    const int n0 = ngrp * 256 + it * NPT;

    float4 xp[8];
    if (it + 1 < NIT) {
      #pragma unroll
      for (int p = 0; p < 4; ++p) {
        int u = p * 512 + t;
        int n = u >> 7, r = (u >> 3) & 15, k8 = u & 7;
        const float* gx = X + (((size_t)(n0 + NPT + n) * 16) + r) * 64 + k8 * 8;
        xp[2 * p]     = *(const float4*)gx;
        xp[2 * p + 1] = *(const float4*)(gx + 4);
      }
    }

    f32x4 acc[2][2];
    #pragma unroll
    for (int rr = 0; rr < 2; ++rr)
      #pragma unroll
      for (int a = 0; a < 2; ++a) acc[rr][a] = (f32x4){0.f, 0.f, 0.f, 0.f};

    #pragma unroll
    for (int rr = 0; rr < 2; ++rr) {
      const int r = r0w + rr;
      #pragma unroll
      for (int ks = 0; ks < 2; ++ks) {
        bf16x8 Bf = *(const bf16x8*)(bufc + (size_t)lr * PITCH_B + r * 128 + ks * 64 + lk * 16);
        acc[rr][0] = __builtin_amdgcn_mfma_f32_16x16x32_bf16(A[rr][ks][0], Bf, acc[rr][0], 0, 0, 0);
        acc[rr][1] = __builtin_amdgcn_mfma_f32_16x16x32_bf16(A[rr][ks][1], Bf, acc[rr][1], 0, 0, 0);
      }
    }
    BARRIER();

    {
      float* Od = (float*)bufc;
      #pragma unroll
      for (int a = 0; a < 2; ++a)
        #pragma unroll
        for (int reg = 0; reg < 4; ++reg) {
          f32x2 v = {acc[0][a][reg], acc[1][a][reg]};
          const int mm = a * 16 + lk * 4 + reg;
          *(f32x2*)(Od + (size_t)lr * OPITCH_DW + mm * 16 + r0w) = v;
        }
    }
    BARRIER();

    {
      const int n  = t >> 5;
      const int j0 = t & 31;
      const float* Or = (const float*)bufc + (size_t)n * OPITCH_DW;
      float* gout = out + ((size_t)(n0 + n)) * 16384 + (size_t)m0 * 16;
      #pragma unroll
      for (int q = 0; q < 4; ++q) {
        const int u = (q * 32 + j0) * 4;
        f32x2 lo = *(const f32x2*)(Or + u);
        f32x2 hi = *(const f32x2*)(Or + u + 2);
        f32x4 v = {lo[0], lo[1], hi[0], hi[1]};
        __builtin_nontemporal_store(v, (f32x4*)(gout + u));
      }
    }

    if (it + 1 < NIT) {
      #pragma unroll
      for (int p = 0; p < 4; ++p) {
        int u = p * 512 + t;
        int n = u >> 7, r = (u >> 3) & 15, k8 = u & 7;
        *(bf16x8*)(bufn + (size_t)n * PITCH_B + r * 128 + k8 * 16) = cvt8v(xp[2 * p], xp[2 * p + 1]);
      }
    }
    BARRIER();
    cur ^= 1;
  }
}

extern "C" void kernel_launch(void* const* d_in, const int* in_sizes, int n_in,
                              void* d_out, int out_size, void* d_ws, size_t ws_size,
                              hipStream_t stream) {
  const float* X = (const float*)d_in[0];   // [4096,1,16,64,1]
  const float* W = (const float*)d_in[1];   // [16,16,64,64]
  float* out = (float*)d_out;               // [4096,1024,16]
  (void)in_sizes; (void)n_in; (void)out_size;

  const size_t XT_BYTES = (size_t)4096 * 16 * 64 * 2;   // 8 MB bf16
  if (ws_size >= XT_BYTES) {
    ushort* Xt = (ushort*)d_ws;
    crxb_pre <<<dim3(1024), dim3(512), 0, stream>>>(X, Xt);
    crxb_main<<<dim3(1024), dim3(512), 0, stream>>>(Xt, W, out);
  } else {
    (void)hipFuncSetAttribute(reinterpret_cast<const void*>(crxb_kernel),
                              hipFuncAttributeMaxDynamicSharedMemorySize, LDS_BYTES);
    crxb_kernel<<<dim3(512), dim3(512), LDS_BYTES, stream>>>(X, W, out);
  }
}

// Round 15
// 72.591 us; speedup vs baseline: 1.0400x; 1.0400x over previous
//
#include <hip/hip_runtime.h>
#include <hip/hip_bf16.h>
#include <stdint.h>

// out[n, m=c*64+i, r] = sum_j (S*W[c,r,i,j]) * X[n,r,j],  S = DELTA_G*DELTA_V
// N=4096, M=1024 (c=16 x i=64), R=16, K=64.  GMIN terms cancel exactly.
//
// Round-15 = round-14 retry with both defects fixed:
//  pre:  X -> Xt (bf16, fragment order) THROUGH LDS so both global read and
//        global write are fully coalesced (r14 pre scattered 16B/lane writes).
//  main: 256-thread blocks, launch_bounds(256,4) -> 128 VGPR cap (r14's
//        (512,8) forced 64 -> spill). 4 waves x 4r = all 16 r per block.
//        LDS = O-tile only (32.9KB) -> 4 blocks/CU; B-frag = contiguous 1KB
//        wave-load from L2-resident Xt; 2 light barriers/iter; nt stores.
//  Fallback to proven round-13 kernel (59.9us) if ws too small.

using bf16x8 = __attribute__((ext_vector_type(8))) short;
using f32x4  = __attribute__((ext_vector_type(4))) float;
using f32x2  = __attribute__((ext_vector_type(2))) float;

#define OPITCH_DW 514
#define BARRIER() asm volatile("s_waitcnt lgkmcnt(0)\n\ts_barrier" ::: "memory")

__device__ inline bf16x8 cvt8v(float4 a, float4 b) {
  union { bf16x8 v; __hip_bfloat162 h[4]; } r;
  r.h[0] = __float22bfloat162_rn(float2{a.x, a.y});
  r.h[1] = __float22bfloat162_rn(float2{a.z, a.w});
  r.h[2] = __float22bfloat162_rn(float2{b.x, b.y});
  r.h[3] = __float22bfloat162_rn(float2{b.z, b.w});
  return r.v;
}

// ---- pre-pass: X[n][r][j] fp32 -> Xt bf16 in fragment order, via LDS ------
// Xt 16B-unit index = tg*2048 + r*128 + ks*64 + lk*16 + lr
//   (frag(tg,r,ks) is then units [base..base+64) -> 1KB contiguous per wave)
__global__ __launch_bounds__(256, 4)
void crxb_pre(const float* __restrict__ X, ushort* __restrict__ Xt) {
  __shared__ char L[16 * 2064];          // [n][r][j8] bf16, pitch 2064
  const int t  = threadIdx.x;
  const int tg = blockIdx.x;             // 0..255 (16 n each)

  #pragma unroll
  for (int p = 0; p < 8; ++p) {          // coalesced global read
    int u = p * 256 + t;                 // 0..2047
    int n = u >> 7, r = (u >> 3) & 15, j8 = u & 7;
    const float* gx = X + (((size_t)(tg * 16 + n) * 16) + r) * 64 + j8 * 8;
    *(bf16x8*)(L + n * 2064 + r * 128 + j8 * 16) =
        cvt8v(*(const float4*)gx, *(const float4*)(gx + 4));
  }
  __syncthreads();

  #pragma unroll
  for (int p = 0; p < 8; ++p) {          // coalesced global write (lr inner)
    int v = p * 256 + t;                 // 0..2047 = r*128 + ks*64 + lk*16 + lr
    int lr = v & 15, lk = (v >> 4) & 3, ks = (v >> 6) & 1, r = v >> 7;
    bf16x8 d = *(const bf16x8*)(L + lr * 2064 + r * 128 + (ks * 4 + lk) * 16);
    *(bf16x8*)(Xt + ((size_t)tg * 2048 + v) * 8) = d;
  }
}

// ---- main: 256 thr, 4 waves x 4r, B from Xt, O-transpose in LDS -----------
__global__ __launch_bounds__(256, 4)
void crxb_main(const ushort* __restrict__ Xt, const float* __restrict__ W,
               float* __restrict__ out) {
  __shared__ float O[16 * OPITCH_DW];    // 32896 B -> 4 blocks/CU

  const int t   = threadIdx.x;
  const int bid = blockIdx.x;
  // 1024 blocks = 32 mt x 32 ng; all 32 m-blocks of one ng on one XCD.
  const int xcd = bid & 7;
  const int ng  = xcd * 4 + ((bid >> 3) & 3);
  const int mt  = bid >> 5;
  const int c  = mt >> 1;
  const int i0 = (mt & 1) << 5;
  const int m0 = mt << 5;

  const int wid = t >> 6;                // 0..3
  const int l   = t & 63;
  const int lr  = l & 15;
  const int lk  = l >> 4;
  const int r0  = wid << 2;              // wave owns r0..r0+3

  const float S = (float)((0.000333 - 3.33e-07) * (3.3 / 255.0));

  // A fragments: (S*W) -> bf16 regs, [rr 0..3][ks][a] = 64 VGPR
  bf16x8 A[4][2][2];
  #pragma unroll
  for (int rr = 0; rr < 4; ++rr)
    #pragma unroll
    for (int ks = 0; ks < 2; ++ks)
      #pragma unroll
      for (int a = 0; a < 2; ++a) {
        const float* gw = W + (((size_t)(c * 16 + r0 + rr) * 64) + (i0 + a * 16 + lr)) * 64
                            + ks * 32 + lk * 8;
        float4 wa = *(const float4*)gw;
        float4 wb = *(const float4*)(gw + 4);
        wa.x *= S; wa.y *= S; wa.z *= S; wa.w *= S;
        wb.x *= S; wb.y *= S; wb.z *= S; wb.w *= S;
        A[rr][ks][a] = cvt8v(wa, wb);
      }

  for (int it = 0; it < 8; ++it) {
    const int tg = ng * 8 + it;
    const int n0 = tg * 16;

    f32x4 acc[4][2];                     // [rr][a] = 32 VGPR
    #pragma unroll
    for (int rr = 0; rr < 4; ++rr) {
      acc[rr][0] = (f32x4){0.f, 0.f, 0.f, 0.f};
      acc[rr][1] = (f32x4){0.f, 0.f, 0.f, 0.f};
    }

    #pragma unroll
    for (int rr = 0; rr < 4; ++rr)
      #pragma unroll
      for (int ks = 0; ks < 2; ++ks) {
        bf16x8 Bf = *(const bf16x8*)(Xt +
            ((size_t)tg * 2048 + (r0 + rr) * 128 + ks * 64 + l) * 8);
        acc[rr][0] = __builtin_amdgcn_mfma_f32_16x16x32_bf16(A[rr][ks][0], Bf, acc[rr][0], 0, 0, 0);
        acc[rr][1] = __builtin_amdgcn_mfma_f32_16x16x32_bf16(A[rr][ks][1], Bf, acc[rr][1], 0, 0, 0);
      }
    BARRIER();                           // prev ep2 reads of O done

    // ep1: r-paired f32x2 (rr 0-1, 2-3) -> O[n=lr][m][r]
    #pragma unroll
    for (int a = 0; a < 2; ++a)
      #pragma unroll
      for (int reg = 0; reg < 4; ++reg) {
        const int mm = a * 16 + lk * 4 + reg;
        f32x2 v0 = {acc[0][a][reg], acc[1][a][reg]};
        f32x2 v1 = {acc[2][a][reg], acc[3][a][reg]};
        *(f32x2*)(O + (size_t)lr * OPITCH_DW + mm * 16 + r0)     = v0;
        *(f32x2*)(O + (size_t)lr * OPITCH_DW + mm * 16 + r0 + 2) = v1;
      }
    BARRIER();

    // ep2: O -> global, coalesced nt stores (512 dw per n-row)
    {
      const int n  = t >> 4;             // 0..15
      const int j0 = t & 15;
      const float* Or = O + (size_t)n * OPITCH_DW;
      float* gout = out + ((size_t)(n0 + n)) * 16384 + (size_t)m0 * 16;
      #pragma unroll
      for (int q = 0; q < 8; ++q) {
        const int u = (q * 16 + j0) * 4;
        f32x2 lo = *(const f32x2*)(Or + u);
        f32x2 hi = *(const f32x2*)(Or + u + 2);
        f32x4 v = {lo[0], lo[1], hi[0], hi[1]};
        __builtin_nontemporal_store(v, (f32x4*)(gout + u));
      }
    }
  }
}

// ---------------- fallback: proven round-13 kernel (59.9us) -----------------
#define NPT 16
#define NIT 16
#define PITCH_B 2064
#define BUFB 33024
#define LDS_BYTES (2*BUFB)

__global__ __launch_bounds__(512, 4)
void crxb_kernel(const float* __restrict__ X, const float* __restrict__ W,
                 float* __restrict__ out) {
  extern __shared__ char smem[];
  const int t   = threadIdx.x;
  const int bid = blockIdx.x;
  const int ngrp = ((bid & 7) << 1) | ((bid >> 3) & 1);
  const int mt   = bid >> 4;
  const int c  = mt >> 1;
  const int i0 = (mt & 1) << 5;
  const int m0 = mt << 5;
  const int wid = t >> 6;
  const int l   = t & 63;
  const int lr  = l & 15;
  const int lk  = l >> 4;
  const int r0w = wid << 1;
  const float S = (float)((0.000333 - 3.33e-07) * (3.3 / 255.0));

  bf16x8 A[2][2][2];
  #pragma unroll
  for (int rr = 0; rr < 2; ++rr)
    #pragma unroll
    for (int ks = 0; ks < 2; ++ks)
      #pragma unroll
      for (int a = 0; a < 2; ++a) {
        const float* gw = W + (((size_t)(c * 16 + r0w + rr) * 64) + (i0 + a * 16 + lr)) * 64
                            + ks * 32 + lk * 8;
        float4 wa = *(const float4*)gw;
        float4 wb = *(const float4*)(gw + 4);
        wa.x *= S; wa.y *= S; wa.z *= S; wa.w *= S;
        wb.x *= S; wb.y *= S; wb.z *= S; wb.w *= S;
        A[rr][ks][a] = cvt8v(wa, wb);
      }

  {
    #pragma unroll
    for (int p = 0; p < 4; ++p) {
      int u = p * 512 + t;
      int n = u >> 7, r = (u >> 3) & 15, k8 = u & 7;
      const float* gx = X + (((size_t)(ngrp * 256 + n) * 16) + r) * 64 + k8 * 8;
      *(bf16x8*)(smem + (size_t)n * PITCH_B + r * 128 + k8 * 16) =
          cvt8v(*(const float4*)gx, *(const float4*)(gx + 4));
    }
  }
  BARRIER();

  int cur = 0;
  for (int it = 0; it < NIT; ++it) {
    char* bufc = smem + cur * BUFB;
    char* bufn = smem + (cur ^ 1) * BUFB;
    const int n0 = ngrp * 256 + it * NPT;

    float4 xp[8];
    if (it + 1 < NIT) {
      #pragma unroll
      for (int p = 0; p < 4; ++p) {
        int u = p * 512 + t;
        int n = u >> 7, r = (u >> 3) & 15, k8 = u & 7;
        const float* gx = X + (((size_t)(n0 + NPT + n) * 16) + r) * 64 + k8 * 8;
        xp[2 * p]     = *(const float4*)gx;
        xp[2 * p + 1] = *(const float4*)(gx + 4);
      }
    }

    f32x4 acc[2][2];
    #pragma unroll
    for (int rr = 0; rr < 2; ++rr)
      #pragma unroll
      for (int a = 0; a < 2; ++a) acc[rr][a] = (f32x4){0.f, 0.f, 0.f, 0.f};

    #pragma unroll
    for (int rr = 0; rr < 2; ++rr) {
      const int r = r0w + rr;
      #pragma unroll
      for (int ks = 0; ks < 2; ++ks) {
        bf16x8 Bf = *(const bf16x8*)(bufc + (size_t)lr * PITCH_B + r * 128 + ks * 64 + lk * 16);
        acc[rr][0] = __builtin_amdgcn_mfma_f32_16x16x32_bf16(A[rr][ks][0], Bf, acc[rr][0], 0, 0, 0);
        acc[rr][1] = __builtin_amdgcn_mfma_f32_16x16x32_bf16(A[rr][ks][1], Bf, acc[rr][1], 0, 0, 0);
      }
    }
    BARRIER();

    {
      float* Od = (float*)bufc;
      #pragma unroll
      for (int a = 0; a < 2; ++a)
        #pragma unroll
        for (int reg = 0; reg < 4; ++reg) {
          f32x2 v = {acc[0][a][reg], acc[1][a][reg]};
          const int mm = a * 16 + lk * 4 + reg;
          *(f32x2*)(Od + (size_t)lr * OPITCH_DW + mm * 16 + r0w) = v;
        }
    }
    BARRIER();

    {
      const int n  = t >> 5;
      const int j0 = t & 31;
      const float* Or = (const float*)bufc + (size_t)n * OPITCH_DW;
      float* gout = out + ((size_t)(n0 + n)) * 16384 + (size_t)m0 * 16;
      #pragma unroll
      for (int q = 0; q < 4; ++q) {
        const int u = (q * 32 + j0) * 4;
        f32x2 lo = *(const f32x2*)(Or + u);
        f32x2 hi = *(const f32x2*)(Or + u + 2);
        f32x4 v = {lo[0], lo[1], hi[0], hi[1]};
        __builtin_nontemporal_store(v, (f32x4*)(gout + u));
      }
    }

    if (it + 1 < NIT) {
      #pragma unroll
      for (int p = 0; p < 4; ++p) {
        int u = p * 512 + t;
        int n = u >> 7, r = (u >> 3) & 15, k8 = u & 7;
        *(bf16x8*)(bufn + (size_t)n * PITCH_B + r * 128 + k8 * 16) = cvt8v(xp[2 * p], xp[2 * p + 1]);
      }
    }
    BARRIER();
    cur ^= 1;
  }
}

extern "C" void kernel_launch(void* const* d_in, const int* in_sizes, int n_in,
                              void* d_out, int out_size, void* d_ws, size_t ws_size,
                              hipStream_t stream) {
  const float* X = (const float*)d_in[0];   // [4096,1,16,64,1]
  const float* W = (const float*)d_in[1];   // [16,16,64,64]
  float* out = (float*)d_out;               // [4096,1024,16]
  (void)in_sizes; (void)n_in; (void)out_size;

  const size_t XT_BYTES = (size_t)4096 * 16 * 64 * 2;   // 8 MB bf16
  if (ws_size >= XT_BYTES) {
    ushort* Xt = (ushort*)d_ws;
    crxb_pre <<<dim3(256),  dim3(256), 0, stream>>>(X, Xt);
    crxb_main<<<dim3(1024), dim3(256), 0, stream>>>(Xt, W, out);
  } else {
    (void)hipFuncSetAttribute(reinterpret_cast<const void*>(crxb_kernel),
                              hipFuncAttributeMaxDynamicSharedMemorySize, LDS_BYTES);
    crxb_kernel<<<dim3(512), dim3(512), LDS_BYTES, stream>>>(X, W, out);
  }
}

// Round 16
// 59.584 us; speedup vs baseline: 1.2670x; 1.2183x over previous
//
#include <hip/hip_runtime.h>
#include <hip/hip_bf16.h>
#include <stdint.h>

// out[n, m=c*64+i, r] = sum_j (S*W[c,r,i,j]) * X[n,r,j],  S = DELTA_G*DELTA_V
// N=4096, M=1024 (c=16 x i=64), R=16, K=64.  GMIN terms cancel exactly.
//
// FINAL = round-8 kernel (best measured: 59.53us, ~89% of the 6.29 TB/s
// measured mixed-stream HBM ceiling at ~335MB total traffic).
// Structure: grid 512 (2 blocks/CU), 512 thr, X bf16 double-buffer in LDS
// (pitch 2064), reg-prefetch of next X tile, 8 MFMAs/wave/iter, LDS output
// transpose (ep1 f32x2 / ep2 coalesced f32x4), 3 light lgkm-only barriers
// per iter (stores never vmcnt-drained), nontemporal output stores,
// XCD-aware block map (X n-group slice pinned per XCD L2), v_cvt_pk bf16
// conversions, S folded into the W register-hoist.
// Falsified alternatives (kept for the record): direct r-in-lane stores
// (3.3x WRITE amplification), single-buffer 4 blk/CU (+48us), 16 thin
// waves (+38us), merged ep2||stage (+17us), two-pass Xt frag layout
// (+13..16us), ep1 bank-conflict fix (neutral), vmcnt(0) barriers (neutral).

using bf16x8 = __attribute__((ext_vector_type(8))) short;
using f32x4  = __attribute__((ext_vector_type(4))) float;
using f32x2  = __attribute__((ext_vector_type(2))) float;

#define NPT 16               // n per iteration tile
#define NIT 16               // iterations per block (16*16 = 256 n per block)
#define PITCH_B 2064         // bytes per n-row in LDS (516 dwords)
#define BUFB 33024           // 16 rows * 2064
#define LDS_BYTES (2*BUFB)   // 66048: double buffer -> 2 blocks/CU

// LDS-only barrier: order ds ops across waves without draining the VM queue.
#define BARRIER() asm volatile("s_waitcnt lgkmcnt(0)\n\ts_barrier" ::: "memory")

__device__ inline bf16x8 cvt8v(float4 a, float4 b) {
  union { bf16x8 v; __hip_bfloat162 h[4]; } r;
  r.h[0] = __float22bfloat162_rn(float2{a.x, a.y});
  r.h[1] = __float22bfloat162_rn(float2{a.z, a.w});
  r.h[2] = __float22bfloat162_rn(float2{b.x, b.y});
  r.h[3] = __float22bfloat162_rn(float2{b.z, b.w});
  return r.v;
}

__global__ __launch_bounds__(512, 4)
void crxb_kernel(const float* __restrict__ X, const float* __restrict__ W,
                 float* __restrict__ out) {
  extern __shared__ char smem[];
  const int t   = threadIdx.x;
  const int bid = blockIdx.x;
  // XCD-aware mapping: each XCD owns 2 n-groups; all 32 m-tiles of a given
  // n-group land on the same XCD -> X slice stays in that XCD's L2.
  const int ngrp = ((bid & 7) << 1) | ((bid >> 3) & 1);  // 0..15, 256 n each
  const int mt   = bid >> 4;                             // 0..31
  const int c  = mt >> 1;
  const int i0 = (mt & 1) << 5;
  const int m0 = mt << 5;

  const int wid = t >> 6;
  const int l   = t & 63;
  const int lr  = l & 15;            // A row (m within 16) / B col (n)
  const int lk  = l >> 4;            // k-subgroup 0..3
  const int r0w = wid << 1;          // wave owns r0w, r0w+1

  const float S = (float)((0.000333 - 3.33e-07) * (3.3 / 255.0));

  // ---- hoist A fragments: (S*W) fp32 global -> bf16 regs (once per block) ----
  bf16x8 A[2][2][2];                 // [rr][ks][a]
  #pragma unroll
  for (int rr = 0; rr < 2; ++rr)
    #pragma unroll
    for (int ks = 0; ks < 2; ++ks)
      #pragma unroll
      for (int a = 0; a < 2; ++a) {
        const float* gw = W + (((size_t)(c * 16 + r0w + rr) * 64) + (i0 + a * 16 + lr)) * 64
                            + ks * 32 + lk * 8;
        float4 wa = *(const float4*)gw;
        float4 wb = *(const float4*)(gw + 4);
        wa.x *= S; wa.y *= S; wa.z *= S; wa.w *= S;
        wb.x *= S; wb.y *= S; wb.z *= S; wb.w *= S;
        A[rr][ks][a] = cvt8v(wa, wb);
      }

  // ---- prologue: stage X tile 0 into buf0 ----
  {
    #pragma unroll
    for (int p = 0; p < 4; ++p) {
      int u = p * 512 + t;                     // 0..2047 bf16x8 units
      int n = u >> 7, r = (u >> 3) & 15, k8 = u & 7;
      const float* gx = X + (((size_t)(ngrp * 256 + n) * 16) + r) * 64 + k8 * 8;
      *(bf16x8*)(smem + (size_t)n * PITCH_B + r * 128 + k8 * 16) =
          cvt8v(*(const float4*)gx, *(const float4*)(gx + 4));
    }
  }
  BARRIER();

  int cur = 0;
  for (int it = 0; it < NIT; ++it) {
    char* bufc = smem + cur * BUFB;
    char* bufn = smem + (cur ^ 1) * BUFB;
    const int n0 = ngrp * 256 + it * NPT;

    // ---- issue next-tile X loads early (latency hides under compute+eps) ----
    float4 xp[8];
    if (it + 1 < NIT) {
      #pragma unroll
      for (int p = 0; p < 4; ++p) {
        int u = p * 512 + t;
        int n = u >> 7, r = (u >> 3) & 15, k8 = u & 7;
        const float* gx = X + (((size_t)(n0 + NPT + n) * 16) + r) * 64 + k8 * 8;
        xp[2 * p]     = *(const float4*)gx;
        xp[2 * p + 1] = *(const float4*)(gx + 4);
      }
    }

    // ---- compute: 32m x 16n, 2 r's per wave, 8 MFMAs ----
    f32x4 acc[2][2];                 // [rr][a]
    #pragma unroll
    for (int rr = 0; rr < 2; ++rr)
      #pragma unroll
      for (int a = 0; a < 2; ++a) acc[rr][a] = (f32x4){0.f, 0.f, 0.f, 0.f};

    #pragma unroll
    for (int rr = 0; rr < 2; ++rr) {
      const int r = r0w + rr;
      #pragma unroll
      for (int ks = 0; ks < 2; ++ks) {
        bf16x8 Bf = *(const bf16x8*)(bufc + (size_t)lr * PITCH_B + r * 128 + ks * 64 + lk * 16);
        acc[rr][0] = __builtin_amdgcn_mfma_f32_16x16x32_bf16(A[rr][ks][0], Bf, acc[rr][0], 0, 0, 0);
        acc[rr][1] = __builtin_amdgcn_mfma_f32_16x16x32_bf16(A[rr][ks][1], Bf, acc[rr][1], 0, 0, 0);
      }
    }
    BARRIER();                       // all reads of bufc done (LDS order only)

    // ---- ep1: acc -> O (fp32) transpose in bufc; r-paired f32x2 stores ----
    #pragma unroll
    for (int a = 0; a < 2; ++a)
      #pragma unroll
      for (int reg = 0; reg < 4; ++reg) {
        f32x2 v = {acc[0][a][reg], acc[1][a][reg]};
        const int mm = a * 16 + lk * 4 + reg;     // m within 32
        *(f32x2*)(bufc + ((size_t)lr * 516 + mm * 16 + r0w) * 4) = v;
      }
    BARRIER();

    // ---- ep2: O -> global, coalesced NONTEMPORAL float4 stores ----
    {
      const int n  = t >> 5;         // 0..15
      const int j0 = t & 31;
      const float* Or = (const float*)(bufc + (size_t)n * PITCH_B);
      float* gout = out + ((size_t)(n0 + n)) * 16384 + (size_t)m0 * 16;
      #pragma unroll
      for (int q = 0; q < 4; ++q) {
        const int u = (q * 32 + j0) * 4;          // dword offset
        f32x4 v = *(const f32x4*)(Or + u);
        __builtin_nontemporal_store(v, (f32x4*)(gout + u));
      }
    }

    // ---- stage next tile: cvt prefetched regs -> bufn ----
    if (it + 1 < NIT) {
      #pragma unroll
      for (int p = 0; p < 4; ++p) {
        int u = p * 512 + t;
        int n = u >> 7, r = (u >> 3) & 15, k8 = u & 7;
        *(bf16x8*)(bufn + (size_t)n * PITCH_B + r * 128 + k8 * 16) = cvt8v(xp[2 * p], xp[2 * p + 1]);
      }
    }
    BARRIER();
    cur ^= 1;
  }
}

extern "C" void kernel_launch(void* const* d_in, const int* in_sizes, int n_in,
                              void* d_out, int out_size, void* d_ws, size_t ws_size,
                              hipStream_t stream) {
  const float* X = (const float*)d_in[0];   // [4096,1,16,64,1]
  const float* W = (const float*)d_in[1];   // [16,16,64,64]
  float* out = (float*)d_out;               // [4096,1024,16]
  (void)in_sizes; (void)n_in; (void)d_ws; (void)ws_size; (void)out_size;

  (void)hipFuncSetAttribute(reinterpret_cast<const void*>(crxb_kernel),
                            hipFuncAttributeMaxDynamicSharedMemorySize, LDS_BYTES);

  crxb_kernel<<<dim3(512), dim3(512), LDS_BYTES, stream>>>(X, W, out);
}